// Round 1
// baseline (501.105 us; speedup 1.0000x reference)
//
#include <hip/hip_runtime.h>

typedef __attribute__((ext_vector_type(4))) float f32x4;
typedef __attribute__((ext_vector_type(8))) short short8;

// Problem dims
#define M_TOT 32768   // B*S
#define N_TOT 2048    // 2*DH
#define K_TOT 1024    // DIN
#define NCHUNK 64
#define CLEN 64       // NCHUNK*CLEN = S = 4096

__device__ __forceinline__ unsigned short f2bf(float f) {
    union { float f; unsigned int u; } a; a.f = f;
    unsigned int r = a.u + 0x7fffu + ((a.u >> 16) & 1u);   // RTNE, finite inputs
    return (unsigned short)(r >> 16);
}
__device__ __forceinline__ float bf2f(unsigned short u) {
    union { unsigned int u; float f; } a; a.u = ((unsigned int)u) << 16;
    return a.f;
}

// ---------------- f32 -> bf16 conversion (vectorized, grid-stride) ----------------
__global__ __launch_bounds__(256) void conv_bf16(const float* __restrict__ in,
                                                 unsigned short* __restrict__ out, int n4) {
    int stride = gridDim.x * 256;
    for (int i = blockIdx.x * 256 + threadIdx.x; i < n4; i += stride) {
        float4 v = reinterpret_cast<const float4*>(in)[i];
        ushort4 o;
        o.x = f2bf(v.x); o.y = f2bf(v.y); o.z = f2bf(v.z); o.w = f2bf(v.w);
        reinterpret_cast<ushort4*>(out)[i] = o;
    }
}

// ---------------- bf16 MFMA GEMM (128x128 tile, BK=32) + activation epilogue ------
// A = x (M x K) bf16 row-major, B = W (N x K) bf16 row-major (B^T layout).
// Epilogue: col<1024 -> zA = sigmoid(gh), col>=1024 -> G = g(gh), both bf16.
__global__ __launch_bounds__(256) void gemm_act(
    const unsigned short* __restrict__ xb, const unsigned short* __restrict__ wb,
    const float* __restrict__ bias,
    unsigned short* __restrict__ zA, unsigned short* __restrict__ G)
{
    __shared__ unsigned short lA[128 * 32];
    __shared__ unsigned short lB[128 * 32];
    const int bid = blockIdx.x;
    const int nt = bid & 15;        // 16 n-tiles (inner: consecutive blocks share A panel in L2/L3)
    const int mt = bid >> 4;        // 256 m-tiles
    const int m0 = mt * 128, n0 = nt * 128;
    const int t = threadIdx.x;
    const int w = t >> 6, l = t & 63;

    f32x4 acc[4][4];
#pragma unroll
    for (int i = 0; i < 4; ++i)
#pragma unroll
        for (int j = 0; j < 4; ++j) acc[i][j] = (f32x4){0.f, 0.f, 0.f, 0.f};

    // staging: 16B/lane, chunk = issue*256 + t; row = chunk>>2, col8 = chunk&3
    const unsigned short* ga = xb + (m0 + (t >> 2)) * 1024 + (t & 3) * 8;
    const unsigned short* gb = wb + (n0 + (t >> 2)) * 1024 + (t & 3) * 8;
    unsigned short* la0 = &lA[t * 8];
    unsigned short* la1 = &lA[2048 + t * 8];
    unsigned short* lb0 = &lB[t * 8];
    unsigned short* lb1 = &lB[2048 + t * 8];

    const int wr = (w >> 1) * 64, wc = (w & 1) * 64;
    const unsigned short* pa = &lA[(wr + (l & 15)) * 32 + (l >> 4) * 8];
    const unsigned short* pb = &lB[(wc + (l & 15)) * 32 + (l >> 4) * 8];

    for (int kt = 0; kt < 32; ++kt) {
        __syncthreads();   // previous iteration's ds_reads complete
        const unsigned short* gak = ga + kt * 32;
        const unsigned short* gbk = gb + kt * 32;
        __builtin_amdgcn_global_load_lds((const __attribute__((address_space(1))) unsigned int*)gak,
                                         (__attribute__((address_space(3))) unsigned int*)la0, 16, 0, 0);
        __builtin_amdgcn_global_load_lds((const __attribute__((address_space(1))) unsigned int*)(gak + 64 * 1024),
                                         (__attribute__((address_space(3))) unsigned int*)la1, 16, 0, 0);
        __builtin_amdgcn_global_load_lds((const __attribute__((address_space(1))) unsigned int*)gbk,
                                         (__attribute__((address_space(3))) unsigned int*)lb0, 16, 0, 0);
        __builtin_amdgcn_global_load_lds((const __attribute__((address_space(1))) unsigned int*)(gbk + 64 * 1024),
                                         (__attribute__((address_space(3))) unsigned int*)lb1, 16, 0, 0);
        asm volatile("s_waitcnt vmcnt(0)" ::: "memory");
        __syncthreads();   // all waves' staging visible

        short8 af[4], bfr[4];
#pragma unroll
        for (int i = 0; i < 4; ++i) af[i]  = *reinterpret_cast<const short8*>(pa + i * 16 * 32);
#pragma unroll
        for (int i = 0; i < 4; ++i) bfr[i] = *reinterpret_cast<const short8*>(pb + i * 16 * 32);
#pragma unroll
        for (int mi = 0; mi < 4; ++mi)
#pragma unroll
            for (int ni = 0; ni < 4; ++ni)
                acc[mi][ni] = __builtin_amdgcn_mfma_f32_16x16x32_bf16(af[mi], bfr[ni], acc[mi][ni], 0, 0, 0);
    }

    // epilogue: C/D layout col = l&15, row = (l>>4)*4 + r   [m89-verified]
    const int col = l & 15;
    const int rbase = (l >> 4) * 4;
#pragma unroll
    for (int ni = 0; ni < 4; ++ni) {
        int gc = n0 + wc + ni * 16 + col;
        float bv = bias[gc];
        bool isGate = gc < 1024;                 // tile-uniform (128 | 1024)
        unsigned short* dst = isGate ? zA : G;
        int cc = isGate ? gc : (gc - 1024);
#pragma unroll
        for (int mi = 0; mi < 4; ++mi) {
            int gr = m0 + wr + mi * 16 + rbase;
#pragma unroll
            for (int r = 0; r < 4; ++r) {
                float v = acc[mi][ni][r] + bv;
                float o;
                if (isGate) o = 1.f / (1.f + __expf(-v));                       // z
                else        o = (v >= 0.f) ? (v + 0.5f) : 1.f / (1.f + __expf(-v)); // g(hidden)
                dst[(gr + r) * 1024 + cc] = f2bf(o);
            }
        }
    }
}

// ---------------- scan pass 1: per-chunk carries (C = prod c, V = local scan) -----
// thread handles 2 channels (ushort2 loads); (b, chunk, hpair)
__global__ __launch_bounds__(256) void scan_carry(
    const unsigned short* __restrict__ zA, const unsigned short* __restrict__ G,
    float* __restrict__ CC, float* __restrict__ CV)
{
    int g = blockIdx.x * 256 + threadIdx.x;
    int hp = g & 511;
    int ck = (g >> 9) & 63;
    int b  = g >> 15;
    int mbase = b * 4096 + ck * CLEN;
    const unsigned int* pa = (const unsigned int*)zA + (size_t)mbase * 512 + hp;
    const unsigned int* pg = (const unsigned int*)G  + (size_t)mbase * 512 + hp;
    float C0 = 1.f, V0 = 0.f, C1 = 1.f, V1 = 0.f;
#pragma unroll 8
    for (int i = 0; i < CLEN; ++i) {
        unsigned int ua = pa[i * 512];
        unsigned int ug = pg[i * 512];
        float a0 = bf2f(ua & 0xffff), a1 = bf2f(ua >> 16);
        float g0 = bf2f(ug & 0xffff), g1 = bf2f(ug >> 16);
        float c0 = 1.f - a0, c1 = 1.f - a1;
        C0 *= c0; V0 = c0 * V0 + a0 * g0;
        C1 *= c1; V1 = c1 * V1 + a1 * g1;
    }
    int idx = (b * 64 + ck) * 1024 + hp * 2;
    *reinterpret_cast<float2*>(CC + idx) = make_float2(C0, C1);
    *reinterpret_cast<float2*>(CV + idx) = make_float2(V0, V1);
}

// ---------------- scan pass 2: sequential scan over 64 chunk carries --------------
__global__ __launch_bounds__(256) void scan_prefix(
    const float* __restrict__ CC, const float* __restrict__ CV,
    const float* __restrict__ h0, float* __restrict__ Hinit)
{
    int g = blockIdx.x * 256 + threadIdx.x;   // 8192 threads
    int h = g & 1023, b = g >> 10;
    float hc = h0[b * 1024 + h];
#pragma unroll 4
    for (int ck = 0; ck < NCHUNK; ++ck) {
        int idx = (b * 64 + ck) * 1024 + h;
        Hinit[idx] = hc;                       // h entering chunk ck
        hc = CC[idx] * hc + CV[idx];
    }
}

// ---------------- scan pass 3: apply within chunk, write output -------------------
__global__ __launch_bounds__(256) void scan_apply(
    const unsigned short* __restrict__ zA, const unsigned short* __restrict__ G,
    const float* __restrict__ Hinit, float* __restrict__ out)
{
    int g = blockIdx.x * 256 + threadIdx.x;
    int hp = g & 511;
    int ck = (g >> 9) & 63;
    int b  = g >> 15;
    int mbase = b * 4096 + ck * CLEN;
    const unsigned int* pa = (const unsigned int*)zA + (size_t)mbase * 512 + hp;
    const unsigned int* pg = (const unsigned int*)G  + (size_t)mbase * 512 + hp;
    float2 hh = *reinterpret_cast<const float2*>(Hinit + (b * 64 + ck) * 1024 + hp * 2);
    float h0v = hh.x, h1v = hh.y;
    float2* po = reinterpret_cast<float2*>(out) + (size_t)mbase * 512 + hp;
#pragma unroll 8
    for (int i = 0; i < CLEN; ++i) {
        unsigned int ua = pa[i * 512];
        unsigned int ug = pg[i * 512];
        float a0 = bf2f(ua & 0xffff), a1 = bf2f(ua >> 16);
        float g0 = bf2f(ug & 0xffff), g1 = bf2f(ug >> 16);
        h0v = (1.f - a0) * h0v + a0 * g0;
        h1v = (1.f - a1) * h1v + a1 * g1;
        po[i * 512] = make_float2(h0v, h1v);
    }
}

extern "C" void kernel_launch(void* const* d_in, const int* in_sizes, int n_in,
                              void* d_out, int out_size, void* d_ws, size_t ws_size,
                              hipStream_t stream)
{
    const float* x    = (const float*)d_in[0];   // (8,4096,1024)
    const float* h0   = (const float*)d_in[1];   // (8,1,1024)
    const float* W    = (const float*)d_in[2];   // (2048,1024)
    const float* bias = (const float*)d_in[3];   // (2048,)
    float* out = (float*)d_out;                  // (8,4096,1024) f32

    // x in bf16 staged into d_out (67 MB <= 134 MB; consumed by gemm before scan_apply writes out)
    unsigned short* xb = (unsigned short*)d_out;

    unsigned short* wb = (unsigned short*)d_ws;                 // 4 MB
    unsigned short* zA = wb + (size_t)2097152;                  // 67 MB  sigmoid(gate) bf16
    unsigned short* G  = zA + (size_t)33554432;                 // 67 MB  g(hidden)     bf16
    float* CC    = (float*)(G + (size_t)33554432);              // 2 MB
    float* CV    = CC + 524288;                                 // 2 MB
    float* Hinit = CV + 524288;                                 // 2 MB

    conv_bf16<<<2048, 256, 0, stream>>>(x, xb, 33554432 / 4);
    conv_bf16<<<512, 256, 0, stream>>>(W, wb, 2097152 / 4);
    gemm_act<<<4096, 256, 0, stream>>>(xb, wb, bias, zA, G);
    scan_carry<<<1024, 256, 0, stream>>>(zA, G, CC, CV);
    scan_prefix<<<32, 256, 0, stream>>>(CC, CV, h0, Hinit);
    scan_apply<<<1024, 256, 0, stream>>>(zA, G, Hinit, out);
}